// Round 11
// baseline (321.069 us; speedup 1.0000x reference)
//
#include <hip/hip_runtime.h>
#include <hip/hip_fp16.h>

#define N_NODES 50000
#define N_EDGES 800000
#define IN_F    512
#define NH      4
#define DH      64
#define HD      256   // NH*DH
#define NEG     0.2f
#define MAXDEG  64    // Poisson(16) max degree bound: P(any node > 64) ~ e^-40 * 5e4 ~ 0
#define NRB     ((N_NODES + 63) / 64)    // 782 row-blocks
#define NROWS_P (NRB * 64)               // 50048 padded rows

typedef __attribute__((ext_vector_type(8))) short bf16x8;
typedef __attribute__((ext_vector_type(4))) float f32x4;

__device__ __forceinline__ unsigned short f2bf(float x) {
    unsigned u = __float_as_uint(x);
    unsigned r = (u + 0x7FFFu + ((u >> 16) & 1u)) >> 16;  // RNE
    return (unsigned short)r;
}
__device__ __forceinline__ float bf2f(unsigned short b) {
    return __uint_as_float((unsigned)b << 16);
}
__device__ __forceinline__ unsigned short f2h(float x) {
    __half h = __float2half_rn(x);
    return *(unsigned short*)&h;
}
__device__ __forceinline__ float h2f(unsigned short us) {
    __half h = *(__half*)&us;
    return __half2float(h);
}

// ---------------- setup: zero counts + W -> WtbT (K-tiled + XOR-swizzled) ----
// WtbT: K-tile t (32KB chunks); within tile granule (col n, k-granule g) at
// linear granule n*8 + (g ^ (n&7)). DMA stages linearly; ds_read applies the
// same XOR -> bank-spread (r2-verified layout).
#define NZB ((N_NODES + 255) / 256)   // 196 zero chunks
__global__ __launch_bounds__(256) void setup_kernel(const float* __restrict__ W,
                                                    unsigned short* __restrict__ WtbT,
                                                    int* __restrict__ counts) {
    int b = blockIdx.x;
    if (b < NZB) {
        int i = b * 256 + threadIdx.x;
        if (i < N_NODES) counts[i] = 0;
    } else {
        int i = (b - NZB) * 256 + threadIdx.x;   // over 512*256
        if (i < IN_F * HD) {
            int k = i >> 8;        // 0..511
            int n = i & 255;       // 0..255
            int t  = k >> 6;       // k-tile
            int kk = k & 63;
            int g  = kk >> 3;      // 8-elem granule within tile
            int w8 = kk & 7;
            WtbT[(size_t)t * 16384 + (n * 8 + (g ^ (n & 7))) * 8 + w8] = f2bf(W[i]);
        }
    }
}

// ---------------- cvt: feat fp32 -> fbf bf16, A-chunk swizzled layout ---------
// fbf chunk (rb, t) = (row/64, k/64): 8KB, granule (r=row&63, g) at linear
// granule r*8 + (g ^ (r&7)). One thread per 16B granule; a wave covers one
// row (2KB coalesced read; each 8-lane t-group writes one permuted 128B line).
// Pad rows >= N_NODES are zero-filled (gemm then needs no A guards).
__global__ __launch_bounds__(256) void cvt_kernel(const float* __restrict__ feat,
                                                  unsigned short* __restrict__ fbf) {
    int gid = blockIdx.x * 256 + threadIdx.x;    // over NROWS_P * 64 granules
    if (gid >= NROWS_P * 64) return;
    int n = gid >> 6;          // padded row
    int l = gid & 63;          // k-granule within row (k = l*8 ..)
    int t = l >> 3;
    int g = l & 7;
    int rb = n >> 6;
    int r  = n & 63;
    bf16x8 s = {};
    if (n < N_NODES) {
        const float* fp = feat + (size_t)n * IN_F + l * 8;
        float4 a = *(const float4*)fp;
        float4 b = *(const float4*)(fp + 4);
        s[0] = (short)f2bf(a.x); s[1] = (short)f2bf(a.y);
        s[2] = (short)f2bf(a.z); s[3] = (short)f2bf(a.w);
        s[4] = (short)f2bf(b.x); s[5] = (short)f2bf(b.y);
        s[6] = (short)f2bf(b.z); s[7] = (short)f2bf(b.w);
    }
    *(bf16x8*)(fbf + ((size_t)rb * 8 + t) * 4096 + (r * 8 + (g ^ (r & 7))) * 8) = s;
}

// ---------------- bf16 MFMA GEMM: ftb = bf16(fbf @ W), el/er fused ------------
// Pure-bf16 m97 pattern: 64x256 tile, BK=64, 4 waves (wave == head == 64-col
// block), acc[4][4]. BOTH operands staged via global_load_lds width-16 into
// single-buffered 40KB LDS (A 8KB + B 32KB) -> 4 blocks/CU (16 waves; cross-
// block overlap hides the barrier drains, m114/m97 mechanism). Zero staging
// VALU, zero guards (fbf pre-padded). XOR-granule reads conflict-free.
__global__ __launch_bounds__(256) void gemm_kernel(const unsigned short* __restrict__ fbf,
                                                   const unsigned short* __restrict__ WtbT,
                                                   const float* __restrict__ attn_l,
                                                   const float* __restrict__ attn_r,
                                                   unsigned short* __restrict__ Cb,
                                                   float* __restrict__ el,
                                                   float* __restrict__ er) {
    __shared__ short A_s[4096];    // 8 KB  (64 rows x 64 k, swizzled granules)
    __shared__ short B_s[16384];   // 32 KB (256 cols x 64 k, swizzled granules)

    const int tid  = threadIdx.x;
    const int lane = tid & 63;
    const int w    = tid >> 6;      // wave id == head id == col block
    const int lm   = lane & 15;
    const int quad = lane >> 4;
    const int rb   = blockIdx.x;
    const int row0 = rb * 64;

    f32x4 acc[4][4] = {};

    for (int t = 0; t < 8; t++) {
        // stage A (2 x 16B/thread) + B (8 x 16B/thread) via DMA
        {
            const char* ga = (const char*)(fbf + ((size_t)rb * 8 + t) * 4096) + tid * 16;
            char* la = (char*)A_s + tid * 16;
#pragma unroll
            for (int s = 0; s < 2; s++)
                __builtin_amdgcn_global_load_lds(
                    (const __attribute__((address_space(1))) unsigned int*)(ga + s * 4096),
                    (__attribute__((address_space(3))) unsigned int*)(la + s * 4096),
                    16, 0, 0);
            const char* gb = (const char*)(WtbT + (size_t)t * 16384) + tid * 16;
            char* lb = (char*)B_s + tid * 16;
#pragma unroll
            for (int s = 0; s < 8; s++)
                __builtin_amdgcn_global_load_lds(
                    (const __attribute__((address_space(1))) unsigned int*)(gb + s * 4096),
                    (__attribute__((address_space(3))) unsigned int*)(lb + s * 4096),
                    16, 0, 0);
        }
        __syncthreads();   // DMA complete (m97-style drain; blocks overlap)

#pragma unroll
        for (int kk2 = 0; kk2 < 2; kk2++) {
            const int g = kk2 * 4 + quad;
            bf16x8 af[4], bfr[4];
#pragma unroll
            for (int i = 0; i < 4; i++) {
                int r = i * 16 + lm;
                af[i] = *(const bf16x8*)(&A_s[(r * 8 + (g ^ (r & 7))) * 8]);
            }
#pragma unroll
            for (int j = 0; j < 4; j++) {
                int n = w * 64 + j * 16 + lm;
                bfr[j] = *(const bf16x8*)(&B_s[(n * 8 + (g ^ (n & 7))) * 8]);
            }
#pragma unroll
            for (int i = 0; i < 4; i++)
#pragma unroll
                for (int j = 0; j < 4; j++)
                    acc[i][j] = __builtin_amdgcn_mfma_f32_16x16x32_bf16(
                        af[i], bfr[j], acc[i][j], 0, 0, 0);
        }
        if (t < 7) __syncthreads();   // protect LDS before next stage
    }

    // C/D layout: col = lane&15, row = quad*4 + reg; store bf16
#pragma unroll
    for (int i = 0; i < 4; i++) {
#pragma unroll
        for (int j = 0; j < 4; j++) {
            int gcol = w * 64 + j * 16 + lm;
#pragma unroll
            for (int r = 0; r < 4; r++) {
                int grow = row0 + i * 16 + quad * 4 + r;
                if (grow < N_NODES)
                    Cb[(size_t)grow * HD + gcol] = f2bf(acc[i][j][r]);
            }
        }
    }

    // fused el/er: wave w == head w; 4-fma per lane + 16-lane shfl_xor reduce
    {
        float al[4], ar[4];
#pragma unroll
        for (int j = 0; j < 4; j++) {
            al[j] = attn_l[w * DH + j * 16 + lm];
            ar[j] = attn_r[w * DH + j * 16 + lm];
        }
#pragma unroll
        for (int i = 0; i < 4; i++) {
#pragma unroll
            for (int r = 0; r < 4; r++) {
                float sl = 0.f, sr = 0.f;
#pragma unroll
                for (int j = 0; j < 4; j++) {
                    sl += acc[i][j][r] * al[j];
                    sr += acc[i][j][r] * ar[j];
                }
#pragma unroll
                for (int off = 8; off > 0; off >>= 1) {
                    sl += __shfl_xor(sl, off);
                    sr += __shfl_xor(sr, off);
                }
                if (lm == 0) {
                    int grow = row0 + i * 16 + quad * 4 + r;
                    if (grow < N_NODES) {
                        el[(size_t)grow * NH + w] = sl;
                        er[(size_t)grow * NH + w] = sr;
                    }
                }
            }
        }
    }
}

// ---------------- edge placement into padded ELL: ONE 16B record per edge -----
// Record (int4): .x = src node, .y = fp16(w0)|fp16(w1)<<16, .z = fp16(w2)|..,
// .w unused. Single scattered 16B store (4 records/line). (byte-identical r10)
__device__ __forceinline__ float lrelu_exp(float x) {
    float y = fmaxf(x, NEG * x);
    return fminf(__expf(y), 60000.f);   // fp16-safe (overflow prob ~1e-9)
}

__global__ __launch_bounds__(256) void place_kernel(const int* __restrict__ src,
                                                    const int* __restrict__ dst,
                                                    const float* __restrict__ el,
                                                    const float* __restrict__ er,
                                                    int* __restrict__ counts,
                                                    int4* __restrict__ recs) {
    int e = blockIdx.x * blockDim.x + threadIdx.x;
    if (e >= N_EDGES) return;
    int u = src[e], v = dst[e];
    float4 l = *(const float4*)(el + (size_t)u * NH);
    float4 r = *(const float4*)(er + (size_t)v * NH);
    float w0 = lrelu_exp(l.x + r.x);
    float w1 = lrelu_exp(l.y + r.y);
    float w2 = lrelu_exp(l.z + r.z);
    float w3 = lrelu_exp(l.w + r.w);
    int4 rec;
    rec.x = u;
    rec.y = (int)(((unsigned)f2h(w1) << 16) | (unsigned)f2h(w0));
    rec.z = (int)(((unsigned)f2h(w3) << 16) | (unsigned)f2h(w2));
    rec.w = 0;
    int j = atomicAdd(&counts[v], 1);
    if (j < MAXDEG) recs[(size_t)v * MAXDEG + j] = rec;
}

// ---------------- aggregation: one wave per dst, slim record loads ------------
// (byte-identical to round 10)
__global__ __launch_bounds__(256) void agg_kernel(const unsigned short* __restrict__ ftb,
                                                  const int4* __restrict__ recs,
                                                  const int* __restrict__ counts,
                                                  float* __restrict__ out) {
    int wv   = (blockIdx.x * blockDim.x + threadIdx.x) >> 6;  // node id
    int lane = threadIdx.x & 63;
    if (wv >= N_NODES) return;

    int deg = counts[wv];
    deg = (deg > MAXDEG) ? MAXDEG : deg;
    const int h    = lane >> 4;
    const int sh   = (h & 1) * 16;       // loop-invariant weight shift
    const int wsel = 1 + (h >> 1);       // loop-invariant weight dword index
    const size_t foff = (size_t)lane * 4;
    const unsigned* rp = (const unsigned*)(recs + (size_t)wv * MAXDEG);

    float4 acc = make_float4(0.f, 0.f, 0.f, 0.f);
    float dsum = 0.f;

    const int n8 = deg >> 3;   // full 8-edge blocks
    for (int b = 0; b < n8; b++) {
        const unsigned* q = rp + b * 32;   // 8 records x 4 dwords
        unsigned u0 = q[0],  p0 = q[0  + wsel];
        unsigned u1 = q[4],  p1 = q[4  + wsel];
        unsigned u2 = q[8],  p2 = q[8  + wsel];
        unsigned u3 = q[12], p3 = q[12 + wsel];
        unsigned u4 = q[16], p4 = q[16 + wsel];
        unsigned u5 = q[20], p5 = q[20 + wsel];
        unsigned u6 = q[24], p6 = q[24 + wsel];
        unsigned u7 = q[28], p7 = q[28 + wsel];
        ushort4 f0 = *(const ushort4*)(ftb + (size_t)u0 * HD + foff);
        ushort4 f1 = *(const ushort4*)(ftb + (size_t)u1 * HD + foff);
        ushort4 f2 = *(const ushort4*)(ftb + (size_t)u2 * HD + foff);
        ushort4 f3 = *(const ushort4*)(ftb + (size_t)u3 * HD + foff);
        ushort4 f4 = *(const ushort4*)(ftb + (size_t)u4 * HD + foff);
        ushort4 f5 = *(const ushort4*)(ftb + (size_t)u5 * HD + foff);
        ushort4 f6 = *(const ushort4*)(ftb + (size_t)u6 * HD + foff);
        ushort4 f7 = *(const ushort4*)(ftb + (size_t)u7 * HD + foff);
        float w0 = h2f((unsigned short)((p0 >> sh) & 0xFFFFu));
        float w1 = h2f((unsigned short)((p1 >> sh) & 0xFFFFu));
        float w2 = h2f((unsigned short)((p2 >> sh) & 0xFFFFu));
        float w3 = h2f((unsigned short)((p3 >> sh) & 0xFFFFu));
        float w4 = h2f((unsigned short)((p4 >> sh) & 0xFFFFu));
        float w5 = h2f((unsigned short)((p5 >> sh) & 0xFFFFu));
        float w6 = h2f((unsigned short)((p6 >> sh) & 0xFFFFu));
        float w7 = h2f((unsigned short)((p7 >> sh) & 0xFFFFu));
        acc.x += w0 * bf2f(f0.x) + w1 * bf2f(f1.x) + w2 * bf2f(f2.x) + w3 * bf2f(f3.x)
               + w4 * bf2f(f4.x) + w5 * bf2f(f5.x) + w6 * bf2f(f6.x) + w7 * bf2f(f7.x);
        acc.y += w0 * bf2f(f0.y) + w1 * bf2f(f1.y) + w2 * bf2f(f2.y) + w3 * bf2f(f3.y)
               + w4 * bf2f(f4.y) + w5 * bf2f(f5.y) + w6 * bf2f(f6.y) + w7 * bf2f(f7.y);
        acc.z += w0 * bf2f(f0.z) + w1 * bf2f(f1.z) + w2 * bf2f(f2.z) + w3 * bf2f(f3.z)
               + w4 * bf2f(f4.z) + w5 * bf2f(f5.z) + w6 * bf2f(f6.z) + w7 * bf2f(f7.z);
        acc.w += w0 * bf2f(f0.w) + w1 * bf2f(f1.w) + w2 * bf2f(f2.w) + w3 * bf2f(f3.w)
               + w4 * bf2f(f4.w) + w5 * bf2f(f5.w) + w6 * bf2f(f6.w) + w7 * bf2f(f7.w);
        dsum += ((w0 + w1) + (w2 + w3)) + ((w4 + w5) + (w6 + w7));
    }
    // predicated-parallel tail (1..7 edges); pad slots are in-bounds (ELL)
    {
        const int p0i = n8 * 8;
        const int rem = deg - p0i;
        if (rem > 0) {
            const unsigned* q = rp + p0i * 4;
            unsigned u0 = q[0];
            unsigned u1 = (1 < rem) ? q[4]  : u0;
            unsigned u2 = (2 < rem) ? q[8]  : u0;
            unsigned u3 = (3 < rem) ? q[12] : u0;
            unsigned u4 = (4 < rem) ? q[16] : u0;
            unsigned u5 = (5 < rem) ? q[20] : u0;
            unsigned u6 = (6 < rem) ? q[24] : u0;
            unsigned p0 = q[0 + wsel];
            unsigned p1 = (1 < rem) ? q[4  + wsel] : 0u;
            unsigned p2 = (2 < rem) ? q[8  + wsel] : 0u;
            unsigned p3 = (3 < rem) ? q[12 + wsel] : 0u;
            unsigned p4 = (4 < rem) ? q[16 + wsel] : 0u;
            unsigned p5 = (5 < rem) ? q[20 + wsel] : 0u;
            unsigned p6 = (6 < rem) ? q[24 + wsel] : 0u;
            ushort4 f0 = *(const ushort4*)(ftb + (size_t)u0 * HD + foff);
            ushort4 f1 = *(const ushort4*)(ftb + (size_t)u1 * HD + foff);
            ushort4 f2 = *(const ushort4*)(ftb + (size_t)u2 * HD + foff);
            ushort4 f3 = *(const ushort4*)(ftb + (size_t)u3 * HD + foff);
            ushort4 f4 = *(const ushort4*)(ftb + (size_t)u4 * HD + foff);
            ushort4 f5 = *(const ushort4*)(ftb + (size_t)u5 * HD + foff);
            ushort4 f6 = *(const ushort4*)(ftb + (size_t)u6 * HD + foff);
            float w0 = h2f((unsigned short)((p0 >> sh) & 0xFFFFu));
            float w1 = h2f((unsigned short)((p1 >> sh) & 0xFFFFu));
            float w2 = h2f((unsigned short)((p2 >> sh) & 0xFFFFu));
            float w3 = h2f((unsigned short)((p3 >> sh) & 0xFFFFu));
            float w4 = h2f((unsigned short)((p4 >> sh) & 0xFFFFu));
            float w5 = h2f((unsigned short)((p5 >> sh) & 0xFFFFu));
            float w6 = h2f((unsigned short)((p6 >> sh) & 0xFFFFu));
            acc.x += w0 * bf2f(f0.x) + w1 * bf2f(f1.x) + w2 * bf2f(f2.x) + w3 * bf2f(f3.x)
                   + w4 * bf2f(f4.x) + w5 * bf2f(f5.x) + w6 * bf2f(f6.x);
            acc.y += w0 * bf2f(f0.y) + w1 * bf2f(f1.y) + w2 * bf2f(f2.y) + w3 * bf2f(f3.y)
                   + w4 * bf2f(f4.y) + w5 * bf2f(f5.y) + w6 * bf2f(f6.y);
            acc.z += w0 * bf2f(f0.z) + w1 * bf2f(f1.z) + w2 * bf2f(f2.z) + w3 * bf2f(f3.z)
                   + w4 * bf2f(f4.z) + w5 * bf2f(f5.z) + w6 * bf2f(f6.z);
            acc.w += w0 * bf2f(f0.w) + w1 * bf2f(f1.w) + w2 * bf2f(f2.w) + w3 * bf2f(f3.w)
                   + w4 * bf2f(f4.w) + w5 * bf2f(f5.w) + w6 * bf2f(f6.w);
            dsum += ((w0 + w1) + (w2 + w3)) + ((w4 + w5) + w6);
        }
    }

    float inv = (dsum > 0.f) ? (1.f / dsum) : 0.f;
    acc.x *= inv; acc.y *= inv; acc.z *= inv; acc.w *= inv;
    *(float4*)(out + (size_t)wv * HD + foff) = acc;
}

// ---------------- launch ----------------
extern "C" void kernel_launch(void* const* d_in, const int* in_sizes, int n_in,
                              void* d_out, int out_size, void* d_ws, size_t ws_size,
                              hipStream_t stream) {
    const float* feat   = (const float*)d_in[0];
    const float* W      = (const float*)d_in[1];
    const float* attn_l = (const float*)d_in[2];
    const float* attn_r = (const float*)d_in[3];
    const int*   src    = (const int*)d_in[4];
    const int*   dst    = (const int*)d_in[5];
    float* out = (float*)d_out;

    char* p = (char*)d_ws;
    auto alloc = [&](size_t bytes) -> char* {
        char* r = p;
        p += (bytes + 255) & ~(size_t)255;
        return r;
    };
    unsigned short* fbf    = (unsigned short*)alloc((size_t)NROWS_P * IN_F * 2);    // 51.3 MB
    unsigned short* ftb    = (unsigned short*)alloc((size_t)N_NODES * HD * 2);      // 25.6 MB
    unsigned short* WtbT   = (unsigned short*)alloc((size_t)IN_F * HD * 2);         // 0.26 MB
    float*          el     = (float*)alloc((size_t)N_NODES * NH * 4);               // 0.8 MB
    float*          er     = (float*)alloc((size_t)N_NODES * NH * 4);               // 0.8 MB
    int4*           recs   = (int4*)alloc((size_t)N_NODES * MAXDEG * 16);           // 51.2 MB
    int*            counts = (int*)alloc((size_t)N_NODES * 4);                      // 0.2 MB

    // 1. setup: zero counts + W -> WtbT swizzled bf16
    setup_kernel<<<NZB + (IN_F * HD + 255) / 256, 256, 0, stream>>>(W, WtbT, counts);
    // 2. cvt: feat -> fbf (bf16, gemm-chunk swizzled, zero-padded rows)
    cvt_kernel<<<(NROWS_P * 64 + 255) / 256, 256, 0, stream>>>(feat, fbf);
    // 3. ftb = fbf @ W + fused el/er (pure-bf16 m97-style, DMA both operands)
    gemm_kernel<<<NRB, 256, 0, stream>>>(fbf, WtbT, attn_l, attn_r, ftb, el, er);
    // 4. edge scores + ELL placement (one 16B record per edge)
    place_kernel<<<(N_EDGES + 255) / 256, 256, 0, stream>>>(src, dst, el, er,
                                                            counts, recs);
    // 5. aggregate per destination node (normalization fused)
    agg_kernel<<<(N_NODES + 3) / 4, 256, 0, stream>>>(ftb, recs, counts, out);
}